// Round 1
// baseline (469.018 us; speedup 1.0000x reference)
//
#include <hip/hip_runtime.h>
#include <math.h>

#define EMB_D 128
#define BN_EPS 1e-5f

// ---------------------------------------------------------------------------
// Kernel 1: per-edge likelihood L[e] = -log(max(||src[s]-dst[d]||^2, 1e-12))
// 32 lanes per edge: each lane loads one float4 (lane*16B) of the 512B row.
// L is written into the logits slot of d_out (overwritten later in-place).
// Per-block double reduction of sum(L), sum(L^2) -> atomicAdd into acc[0..1].
// ---------------------------------------------------------------------------
__global__ void edge_l_kernel(const float* __restrict__ src,
                              const float* __restrict__ dst,
                              const int*   __restrict__ g,
                              long long E,
                              float*  __restrict__ l_out,   // d_out + 3E
                              double* __restrict__ acc)     // acc[0]=sumL acc[1]=sumL2
{
    const int lane = threadIdx.x & 31;          // lane within 32-lane group
    const int grp  = threadIdx.x >> 5;          // 0..7 groups per 256-thread block
    const long long stride = (long long)gridDim.x * 8;

    double sumL = 0.0, sumL2 = 0.0;

    for (long long e = (long long)blockIdx.x * 8 + grp; e < E; e += stride) {
        const int s = g[e];
        const int d = g[E + e];
        const float4 a = ((const float4*)(src + (long long)s * EMB_D))[lane];
        const float4 b = ((const float4*)(dst + (long long)d * EMB_D))[lane];
        const float dx = a.x - b.x;
        const float dy = a.y - b.y;
        const float dz = a.z - b.z;
        const float dw = a.w - b.w;
        float p = dx * dx + dy * dy + dz * dz + dw * dw;
        // reduce across the 32-lane group (masks <32 stay within aligned group)
        #pragma unroll
        for (int m = 16; m >= 1; m >>= 1)
            p += __shfl_xor(p, m, 64);
        if (lane == 0) {
            const float d2 = fmaxf(p, 1e-12f);
            const float L  = -logf(d2);
            l_out[e] = L;
            sumL  += (double)L;
            sumL2 += (double)L * (double)L;
        }
    }

    __shared__ double sA[256];
    __shared__ double sB[256];
    sA[threadIdx.x] = sumL;
    sB[threadIdx.x] = sumL2;
    __syncthreads();
    for (int ofs = 128; ofs >= 1; ofs >>= 1) {
        if ((int)threadIdx.x < ofs) {
            sA[threadIdx.x] += sA[threadIdx.x + ofs];
            sB[threadIdx.x] += sB[threadIdx.x + ofs];
        }
        __syncthreads();
    }
    if (threadIdx.x == 0) {
        atomicAdd(&acc[0], sA[0]);
        atomicAdd(&acc[1], sB[0]);
    }
}

// ---------------------------------------------------------------------------
// Kernel 2: logits = bn_w * (L - mu) * rsqrt(var + eps) + bn_b   (in place)
//           accumulate sum(sigmoid(logits)) into acc[2]
// ---------------------------------------------------------------------------
__global__ void bn_sig_kernel(float* __restrict__ logits,       // in: L, out: logits
                              const double* __restrict__ acc,
                              double* __restrict__ sig_acc,     // &acc[2]
                              const float* __restrict__ bn_w,
                              const float* __restrict__ bn_b,
                              long long E)
{
    const long long i = (long long)blockIdx.x * blockDim.x + threadIdx.x;
    const double mu  = acc[0] / (double)E;
    const double var = acc[1] / (double)E - mu * mu;
    const float inv  = (float)(1.0 / sqrt(var + (double)BN_EPS));
    const float w = bn_w[0];
    const float b = bn_b[0];

    double sig = 0.0;
    if (i < E) {
        const float L = logits[i];
        const float z = w * (L - (float)mu) * inv + b;
        logits[i] = z;
        sig = (double)(1.0f / (1.0f + expf(-z)));
    }

    __shared__ double sS[256];
    sS[threadIdx.x] = sig;
    __syncthreads();
    for (int ofs = 128; ofs >= 1; ofs >>= 1) {
        if ((int)threadIdx.x < ofs)
            sS[threadIdx.x] += sS[threadIdx.x + ofs];
        __syncthreads();
    }
    if (threadIdx.x == 0)
        atomicAdd(sig_acc, sS[0]);
}

// ---------------------------------------------------------------------------
// Kernel 3: edge_weights = sigmoid(logits) * (E / sum_sigmoid)
// ---------------------------------------------------------------------------
__global__ void norm_kernel(const float* __restrict__ logits,
                            float* __restrict__ ew,             // d_out + 2E
                            const double* __restrict__ sig_acc,
                            long long E)
{
    const long long i = (long long)blockIdx.x * blockDim.x + threadIdx.x;
    if (i < E) {
        const float scale = (float)((double)E / sig_acc[0]);
        const float s = 1.0f / (1.0f + expf(-logits[i]));
        ew[i] = s * scale;
    }
}

// ---------------------------------------------------------------------------
// Kernel 4: copy graph indices to d_out[0 .. 2E) as float (exact: idx < 2^24)
// ---------------------------------------------------------------------------
__global__ void copy_graph_kernel(const int* __restrict__ g,
                                  float* __restrict__ out,
                                  long long n)
{
    long long i = 4LL * ((long long)blockIdx.x * blockDim.x + threadIdx.x);
    if (i + 3 < n) {
        const int4 v = *(const int4*)(g + i);
        float4 f;
        f.x = (float)v.x; f.y = (float)v.y; f.z = (float)v.z; f.w = (float)v.w;
        *(float4*)(out + i) = f;
    } else {
        for (; i < n; ++i) out[i] = (float)g[i];
    }
}

extern "C" void kernel_launch(void* const* d_in, const int* in_sizes, int n_in,
                              void* d_out, int out_size, void* d_ws, size_t ws_size,
                              hipStream_t stream) {
    const float* src  = (const float*)d_in[0];
    const float* dst  = (const float*)d_in[1];
    const int*   g    = (const int*)d_in[2];
    const float* bn_w = (const float*)d_in[3];
    const float* bn_b = (const float*)d_in[4];

    const long long E = (long long)in_sizes[2] / 2;

    float* out        = (float*)d_out;
    float* out_graph  = out;            // [0, 2E)
    float* out_ew     = out + 2 * E;    // [2E, 3E)
    float* out_logits = out + 3 * E;    // [3E, 4E)  (holds L temporarily)

    double* acc = (double*)d_ws;        // acc[0]=sumL acc[1]=sumL2 acc[2]=sumSig
    hipMemsetAsync(d_ws, 0, 3 * sizeof(double), stream);

    // graph copy (independent, small)
    {
        const long long n = 2 * E;
        const long long nvec = (n + 3) / 4;
        const int blocks = (int)((nvec + 255) / 256);
        copy_graph_kernel<<<blocks, 256, 0, stream>>>(g, out_graph, n);
    }

    // pass 1: gather + L + sum/sumsq
    edge_l_kernel<<<4096, 256, 0, stream>>>(src, dst, g, E, out_logits, acc);

    // pass 2: batch-norm + sigmoid sum
    {
        const int blocks = (int)((E + 255) / 256);
        bn_sig_kernel<<<blocks, 256, 0, stream>>>(out_logits, acc, &acc[2],
                                                  bn_w, bn_b, E);
    }

    // pass 3: normalize edge weights
    {
        const int blocks = (int)((E + 255) / 256);
        norm_kernel<<<blocks, 256, 0, stream>>>(out_logits, out_ew, &acc[2], E);
    }
}

// Round 2
// 377.169 us; speedup vs baseline: 1.2435x; 1.2435x over previous
//
#include <hip/hip_runtime.h>
#include <math.h>

#define EMB_D 128
#define BN_EPS 1e-5f

__device__ __forceinline__ float dot4diff(float4 a, float4 b) {
    float dx = a.x - b.x, dy = a.y - b.y, dz = a.z - b.z, dw = a.w - b.w;
    return fmaf(dx, dx, fmaf(dy, dy, fmaf(dz, dz, dw * dw)));
}

// ---------------------------------------------------------------------------
// Kernel 1: per-edge likelihood L[e] = -log(max(||src[s]-dst[d]||^2, 1e-12))
// 8 lanes per edge: lane loads 4 float4 of src row + 4 of dst row (ILP=8),
// 3-step shuffle reduce within the 8-lane group. 8 edges per wave.
// Indices for the next iteration are prefetched to hide the idx->row chain.
// Per-block double reduction of sum(L), sum(L^2) -> atomicAdd into acc[0..1].
// ---------------------------------------------------------------------------
__global__ void edge_l_kernel(const float* __restrict__ src,
                              const float* __restrict__ dst,
                              const int*   __restrict__ g,
                              long long E,
                              float*  __restrict__ l_out,   // d_out + 3E
                              double* __restrict__ acc)     // acc[0]=sumL acc[1]=sumL2
{
    const int sub  = threadIdx.x & 7;   // lane within 8-lane edge group
    const int egrp = threadIdx.x >> 3;  // 0..31 edge slot within block
    const long long stride = (long long)gridDim.x * 32;

    double sumL = 0.0, sumL2 = 0.0;

    long long e = (long long)blockIdx.x * 32 + egrp;
    int s = 0, d = 0;
    if (e < E) { s = g[e]; d = g[E + e]; }

    while (e < E) {
        // prefetch next iteration's indices (independent of current row loads)
        const long long en = e + stride;
        int sn = 0, dn = 0;
        if (en < E) { sn = g[en]; dn = g[E + en]; }

        const float4* sa = (const float4*)(src + (long long)s * EMB_D);
        const float4* sb = (const float4*)(dst + (long long)d * EMB_D);
        const float4 a0 = sa[sub];      const float4 b0 = sb[sub];
        const float4 a1 = sa[sub + 8];  const float4 b1 = sb[sub + 8];
        const float4 a2 = sa[sub + 16]; const float4 b2 = sb[sub + 16];
        const float4 a3 = sa[sub + 24]; const float4 b3 = sb[sub + 24];

        float p = dot4diff(a0, b0) + dot4diff(a1, b1)
                + dot4diff(a2, b2) + dot4diff(a3, b3);

        p += __shfl_xor(p, 1, 64);
        p += __shfl_xor(p, 2, 64);
        p += __shfl_xor(p, 4, 64);

        if (sub == 0) {
            const float L = -logf(fmaxf(p, 1e-12f));
            l_out[e] = L;
            sumL  += (double)L;
            sumL2 += (double)L * (double)L;
        }

        e = en; s = sn; d = dn;
    }

    __shared__ double sA[256];
    __shared__ double sB[256];
    sA[threadIdx.x] = sumL;
    sB[threadIdx.x] = sumL2;
    __syncthreads();
    for (int ofs = 128; ofs >= 1; ofs >>= 1) {
        if ((int)threadIdx.x < ofs) {
            sA[threadIdx.x] += sA[threadIdx.x + ofs];
            sB[threadIdx.x] += sB[threadIdx.x + ofs];
        }
        __syncthreads();
    }
    if (threadIdx.x == 0) {
        atomicAdd(&acc[0], sA[0]);
        atomicAdd(&acc[1], sB[0]);
    }
}

// ---------------------------------------------------------------------------
// Kernel 2: (a) copy graph -> float out[0..2E)   (grid-stride, int4)
//           (b) logits = bn_w*(L-mu)*rsqrt(var+eps)+bn_b (in place),
//               sigmoid -> ew slot, accumulate sum(sigmoid) into acc[2]
// ---------------------------------------------------------------------------
__global__ void bn_sig_copy_kernel(float* __restrict__ logits,   // in: L, out: z
                                   float* __restrict__ ew,       // out: sigmoid(z)
                                   const int* __restrict__ g,
                                   float* __restrict__ out_graph,
                                   const double* __restrict__ acc,
                                   double* __restrict__ sig_acc, // &acc[2]
                                   const float* __restrict__ bn_w,
                                   const float* __restrict__ bn_b,
                                   long long E)
{
    const long long nthreads = (long long)gridDim.x * blockDim.x;
    const long long tid0 = (long long)blockIdx.x * blockDim.x + threadIdx.x;

    // phase A: graph copy (2E ints -> floats), vectorized
    const long long nvec = (2 * E) / 4;
    for (long long i = tid0; i < nvec; i += nthreads) {
        const int4 v = ((const int4*)g)[i];
        float4 f;
        f.x = (float)v.x; f.y = (float)v.y; f.z = (float)v.z; f.w = (float)v.w;
        ((float4*)out_graph)[i] = f;
    }
    for (long long i = nvec * 4 + tid0; i < 2 * E; i += nthreads)
        out_graph[i] = (float)g[i];

    // phase B: BN params computed once per block
    __shared__ float s_mu, s_inv, s_w, s_b;
    if (threadIdx.x == 0) {
        const double mu  = acc[0] / (double)E;
        const double var = acc[1] / (double)E - mu * mu;
        s_mu  = (float)mu;
        s_inv = (float)(1.0 / sqrt(var + (double)BN_EPS));
        s_w   = bn_w[0];
        s_b   = bn_b[0];
    }
    __syncthreads();
    const float mu = s_mu, inv = s_inv, w = s_w, b = s_b;

    double sig = 0.0;
    for (long long i = tid0; i < E; i += nthreads) {
        const float L = logits[i];
        const float z = w * (L - mu) * inv + b;
        logits[i] = z;
        const float sg = 1.0f / (1.0f + expf(-z));
        ew[i] = sg;
        sig += (double)sg;
    }

    __shared__ double sS[256];
    sS[threadIdx.x] = sig;
    __syncthreads();
    for (int ofs = 128; ofs >= 1; ofs >>= 1) {
        if ((int)threadIdx.x < ofs)
            sS[threadIdx.x] += sS[threadIdx.x + ofs];
        __syncthreads();
    }
    if (threadIdx.x == 0)
        atomicAdd(sig_acc, sS[0]);
}

// ---------------------------------------------------------------------------
// Kernel 3: ew *= E / sum_sigmoid   (in place, vectorized)
// ---------------------------------------------------------------------------
__global__ void norm_kernel(float* __restrict__ ew,
                            const double* __restrict__ sig_acc,
                            long long E)
{
    const long long nthreads = (long long)gridDim.x * blockDim.x;
    const long long tid0 = (long long)blockIdx.x * blockDim.x + threadIdx.x;
    const float scale = (float)((double)E / sig_acc[0]);

    const long long nvec = E / 4;
    for (long long i = tid0; i < nvec; i += nthreads) {
        float4 v = ((float4*)ew)[i];
        v.x *= scale; v.y *= scale; v.z *= scale; v.w *= scale;
        ((float4*)ew)[i] = v;
    }
    for (long long i = nvec * 4 + tid0; i < E; i += nthreads)
        ew[i] *= scale;
}

extern "C" void kernel_launch(void* const* d_in, const int* in_sizes, int n_in,
                              void* d_out, int out_size, void* d_ws, size_t ws_size,
                              hipStream_t stream) {
    const float* src  = (const float*)d_in[0];
    const float* dst  = (const float*)d_in[1];
    const int*   g    = (const int*)d_in[2];
    const float* bn_w = (const float*)d_in[3];
    const float* bn_b = (const float*)d_in[4];

    const long long E = (long long)in_sizes[2] / 2;

    float* out        = (float*)d_out;
    float* out_graph  = out;            // [0, 2E)
    float* out_ew     = out + 2 * E;    // [2E, 3E)
    float* out_logits = out + 3 * E;    // [3E, 4E)  (holds L temporarily)

    double* acc = (double*)d_ws;        // acc[0]=sumL acc[1]=sumL2 acc[2]=sumSig
    hipMemsetAsync(d_ws, 0, 3 * sizeof(double), stream);

    // pass 1: gather + L + sum/sumsq
    edge_l_kernel<<<4096, 256, 0, stream>>>(src, dst, g, E, out_logits, acc);

    // pass 2: graph copy + batch-norm + sigmoid (+sum)
    bn_sig_copy_kernel<<<2048, 256, 0, stream>>>(out_logits, out_ew, g, out_graph,
                                                 acc, &acc[2], bn_w, bn_b, E);

    // pass 3: normalize edge weights in place
    norm_kernel<<<2048, 256, 0, stream>>>(out_ew, &acc[2], E);
}

// Round 3
// 293.020 us; speedup vs baseline: 1.6006x; 1.2872x over previous
//
#include <hip/hip_runtime.h>
#include <math.h>

#define EMB_D 128
#define BN_EPS 1e-5f

typedef float v2f __attribute__((ext_vector_type(2)));

#if defined(__has_builtin)
#if __has_builtin(__builtin_amdgcn_cvt_pk_f32_fp8) && __has_builtin(__builtin_amdgcn_cvt_pk_fp8_f32)
#define FP8_HW 1
#endif
#endif

// ---------------- fp8 e4m3 helpers (HW cvt with SW fallback) ----------------
__device__ __forceinline__ unsigned int sw_f32_to_fp8(float x) {
    unsigned int u = __float_as_uint(x);
    unsigned int s = u >> 31;
    int e = (int)((u >> 23) & 0xff) - 127;
    unsigned int m = u & 0x7fffff;
    // RNE to 3 mantissa bits
    m += 0x7FFFF + ((m >> 20) & 1);
    if (m >> 23) { m = 0; e += 1; }
    int e8 = e + 7;
    if (e8 <= 0) return s << 7;                    // flush subnormals
    if (e8 >= 15) return (s << 7) | 0x7E;          // clamp to 448
    return (s << 7) | ((unsigned)e8 << 3) | (m >> 20);
}

__device__ __forceinline__ float sw_fp8_to_f32(unsigned int v) {
    unsigned int s = (v >> 7) & 1, e = (v >> 3) & 15, m = v & 7;
    if (e == 0) return 0.0f;                       // flush subnormals
    unsigned int bits = (s << 31) | ((e - 7 + 127) << 23) | (m << 20);
    return __uint_as_float(bits);
}

// pack float4 -> 4 fp8 bytes in one dword (layout self-consistent with decode)
__device__ __forceinline__ unsigned int pack4_fp8(float4 v) {
#ifdef FP8_HW
    unsigned int o = 0;
    o = (unsigned int)__builtin_amdgcn_cvt_pk_fp8_f32(v.x, v.y, (int)o, false);
    o = (unsigned int)__builtin_amdgcn_cvt_pk_fp8_f32(v.z, v.w, (int)o, true);
    return o;
#else
    return sw_f32_to_fp8(v.x) | (sw_f32_to_fp8(v.y) << 8) |
           (sw_f32_to_fp8(v.z) << 16) | (sw_f32_to_fp8(v.w) << 24);
#endif
}

// sum of squared differences of the 4 fp8 elements packed in ua vs ub
__device__ __forceinline__ float fp8x4_d2(unsigned int ua, unsigned int ub) {
#ifdef FP8_HW
    v2f a0 = __builtin_amdgcn_cvt_pk_f32_fp8((int)ua, false);
    v2f a1 = __builtin_amdgcn_cvt_pk_f32_fp8((int)ua, true);
    v2f b0 = __builtin_amdgcn_cvt_pk_f32_fp8((int)ub, false);
    v2f b1 = __builtin_amdgcn_cvt_pk_f32_fp8((int)ub, true);
    float dx = a0.x - b0.x, dy = a0.y - b0.y;
    float dz = a1.x - b1.x, dw = a1.y - b1.y;
#else
    float dx = sw_fp8_to_f32(ua & 0xff)         - sw_fp8_to_f32(ub & 0xff);
    float dy = sw_fp8_to_f32((ua >> 8) & 0xff)  - sw_fp8_to_f32((ub >> 8) & 0xff);
    float dz = sw_fp8_to_f32((ua >> 16) & 0xff) - sw_fp8_to_f32((ub >> 16) & 0xff);
    float dw = sw_fp8_to_f32(ua >> 24)          - sw_fp8_to_f32(ub >> 24);
#endif
    return fmaf(dx, dx, fmaf(dy, dy, fmaf(dz, dz, dw * dw)));
}

__device__ __forceinline__ float chunk_d2(uint4 a, uint4 b) {
    return fp8x4_d2(a.x, b.x) + fp8x4_d2(a.y, b.y)
         + fp8x4_d2(a.z, b.z) + fp8x4_d2(a.w, b.w);
}

// ---------------------------------------------------------------------------
// K0: streaming prep — convert src/dst f32 -> fp8 tables in ws, copy graph
//     indices -> float out[0..2E), zero the accumulator scalars.
// ---------------------------------------------------------------------------
__global__ void prep_kernel(const float* __restrict__ src,
                            const float* __restrict__ dst,
                            unsigned int* __restrict__ src8,   // nElem/4 dwords
                            unsigned int* __restrict__ dst8,
                            long long nElem,                   // N*128
                            const int* __restrict__ g,
                            float* __restrict__ out_graph,
                            long long twoE,
                            double* __restrict__ acc)
{
    if (blockIdx.x == 0 && threadIdx.x < 3) acc[threadIdx.x] = 0.0;

    const long long nthreads = (long long)gridDim.x * blockDim.x;
    const long long tid0 = (long long)blockIdx.x * blockDim.x + threadIdx.x;

    const long long nvec = nElem / 4;
    for (long long i = tid0; i < nvec; i += nthreads)
        src8[i] = pack4_fp8(((const float4*)src)[i]);
    for (long long i = tid0; i < nvec; i += nthreads)
        dst8[i] = pack4_fp8(((const float4*)dst)[i]);

    const long long gvec = twoE / 4;
    for (long long i = tid0; i < gvec; i += nthreads) {
        const int4 v = ((const int4*)g)[i];
        float4 f;
        f.x = (float)v.x; f.y = (float)v.y; f.z = (float)v.z; f.w = (float)v.w;
        ((float4*)out_graph)[i] = f;
    }
    for (long long i = gvec * 4 + tid0; i < twoE; i += nthreads)
        out_graph[i] = (float)g[i];
}

// ---------------------------------------------------------------------------
// K1 (fp8): L[e] = -log(max(||src[s]-dst[d]||^2, 1e-12)); 2 lanes per edge,
// each lane loads 4x16B of src row + 4x16B of dst row (fp8, 128B rows),
// 1-step shuffle reduce; 32 edges per wave. Index prefetch hides idx->row.
// Block double-reduction of sum(L), sum(L^2) -> atomicAdd into acc[0..1].
// ---------------------------------------------------------------------------
__global__ void edge_l_fp8_kernel(const unsigned char* __restrict__ src8,
                                  const unsigned char* __restrict__ dst8,
                                  const int* __restrict__ g,
                                  long long E,
                                  float*  __restrict__ l_out,
                                  double* __restrict__ acc)
{
    const int sub = threadIdx.x & 1;
    const int eg  = threadIdx.x >> 1;            // 0..127 edge slot in block
    const long long stride = (long long)gridDim.x * 128;

    double sumL = 0.0, sumL2 = 0.0;

    long long e = (long long)blockIdx.x * 128 + eg;
    int s = 0, d = 0;
    if (e < E) { s = g[e]; d = g[E + e]; }

    while (e < E) {
        const long long en = e + stride;
        int sn = 0, dn = 0;
        if (en < E) { sn = g[en]; dn = g[E + en]; }

        const uint4* sa = (const uint4*)(src8 + (long long)s * 128) + sub * 4;
        const uint4* sb = (const uint4*)(dst8 + (long long)d * 128) + sub * 4;
        const uint4 a0 = sa[0], a1 = sa[1], a2 = sa[2], a3 = sa[3];
        const uint4 b0 = sb[0], b1 = sb[1], b2 = sb[2], b3 = sb[3];

        float p = chunk_d2(a0, b0) + chunk_d2(a1, b1)
                + chunk_d2(a2, b2) + chunk_d2(a3, b3);

        p += __shfl_xor(p, 1, 64);

        if (sub == 0) {
            const float L = -logf(fmaxf(p, 1e-12f));
            l_out[e] = L;
            sumL  += (double)L;
            sumL2 += (double)L * (double)L;
        }
        e = en; s = sn; d = dn;
    }

    __shared__ double sA[256];
    __shared__ double sB[256];
    sA[threadIdx.x] = sumL;
    sB[threadIdx.x] = sumL2;
    __syncthreads();
    for (int ofs = 128; ofs >= 1; ofs >>= 1) {
        if ((int)threadIdx.x < ofs) {
            sA[threadIdx.x] += sA[threadIdx.x + ofs];
            sB[threadIdx.x] += sB[threadIdx.x + ofs];
        }
        __syncthreads();
    }
    if (threadIdx.x == 0) {
        atomicAdd(&acc[0], sA[0]);
        atomicAdd(&acc[1], sB[0]);
    }
}

// ---------------------------------------------------------------------------
// K1 fallback (f32 tables in-place) if ws too small for fp8 tables.
// ---------------------------------------------------------------------------
__global__ void edge_l_kernel(const float* __restrict__ src,
                              const float* __restrict__ dst,
                              const int*   __restrict__ g,
                              long long E,
                              float*  __restrict__ l_out,
                              double* __restrict__ acc)
{
    const int sub  = threadIdx.x & 7;
    const int egrp = threadIdx.x >> 3;
    const long long stride = (long long)gridDim.x * 32;

    double sumL = 0.0, sumL2 = 0.0;

    long long e = (long long)blockIdx.x * 32 + egrp;
    int s = 0, d = 0;
    if (e < E) { s = g[e]; d = g[E + e]; }

    while (e < E) {
        const long long en = e + stride;
        int sn = 0, dn = 0;
        if (en < E) { sn = g[en]; dn = g[E + en]; }

        const float4* sa = (const float4*)(src + (long long)s * EMB_D);
        const float4* sb = (const float4*)(dst + (long long)d * EMB_D);
        const float4 a0 = sa[sub];      const float4 b0 = sb[sub];
        const float4 a1 = sa[sub + 8];  const float4 b1 = sb[sub + 8];
        const float4 a2 = sa[sub + 16]; const float4 b2 = sb[sub + 16];
        const float4 a3 = sa[sub + 24]; const float4 b3 = sb[sub + 24];

        float dx, dy, dz, dw, p = 0.f;
        dx = a0.x-b0.x; dy = a0.y-b0.y; dz = a0.z-b0.z; dw = a0.w-b0.w;
        p += fmaf(dx,dx,fmaf(dy,dy,fmaf(dz,dz,dw*dw)));
        dx = a1.x-b1.x; dy = a1.y-b1.y; dz = a1.z-b1.z; dw = a1.w-b1.w;
        p += fmaf(dx,dx,fmaf(dy,dy,fmaf(dz,dz,dw*dw)));
        dx = a2.x-b2.x; dy = a2.y-b2.y; dz = a2.z-b2.z; dw = a2.w-b2.w;
        p += fmaf(dx,dx,fmaf(dy,dy,fmaf(dz,dz,dw*dw)));
        dx = a3.x-b3.x; dy = a3.y-b3.y; dz = a3.z-b3.z; dw = a3.w-b3.w;
        p += fmaf(dx,dx,fmaf(dy,dy,fmaf(dz,dz,dw*dw)));

        p += __shfl_xor(p, 1, 64);
        p += __shfl_xor(p, 2, 64);
        p += __shfl_xor(p, 4, 64);

        if (sub == 0) {
            const float L = -logf(fmaxf(p, 1e-12f));
            l_out[e] = L;
            sumL  += (double)L;
            sumL2 += (double)L * (double)L;
        }
        e = en; s = sn; d = dn;
    }

    __shared__ double sA[256];
    __shared__ double sB[256];
    sA[threadIdx.x] = sumL;
    sB[threadIdx.x] = sumL2;
    __syncthreads();
    for (int ofs = 128; ofs >= 1; ofs >>= 1) {
        if ((int)threadIdx.x < ofs) {
            sA[threadIdx.x] += sA[threadIdx.x + ofs];
            sB[threadIdx.x] += sB[threadIdx.x + ofs];
        }
        __syncthreads();
    }
    if (threadIdx.x == 0) {
        atomicAdd(&acc[0], sA[0]);
        atomicAdd(&acc[1], sB[0]);
    }
}

__global__ void copy_graph_kernel(const int* __restrict__ g,
                                  float* __restrict__ out,
                                  long long n)
{
    const long long nthreads = (long long)gridDim.x * blockDim.x;
    const long long tid0 = (long long)blockIdx.x * blockDim.x + threadIdx.x;
    const long long nvec = n / 4;
    for (long long i = tid0; i < nvec; i += nthreads) {
        const int4 v = ((const int4*)g)[i];
        float4 f;
        f.x = (float)v.x; f.y = (float)v.y; f.z = (float)v.z; f.w = (float)v.w;
        ((float4*)out)[i] = f;
    }
    for (long long i = nvec * 4 + tid0; i < n; i += nthreads)
        out[i] = (float)g[i];
}

// ---------------------------------------------------------------------------
// K2: logits = w*(L-mu)*rsqrt(var+eps)+b (in place); sigmoid -> ew slot;
//     accumulate sum(sigmoid) into acc[2].
// ---------------------------------------------------------------------------
__global__ void bn_sig_kernel(float* __restrict__ logits,
                              float* __restrict__ ew,
                              const double* __restrict__ acc,
                              double* __restrict__ sig_acc,
                              const float* __restrict__ bn_w,
                              const float* __restrict__ bn_b,
                              long long E)
{
    const long long nthreads = (long long)gridDim.x * blockDim.x;
    const long long tid0 = (long long)blockIdx.x * blockDim.x + threadIdx.x;

    __shared__ float s_mu, s_inv, s_w, s_b;
    if (threadIdx.x == 0) {
        const double mu  = acc[0] / (double)E;
        const double var = acc[1] / (double)E - mu * mu;
        s_mu  = (float)mu;
        s_inv = (float)(1.0 / sqrt(var + (double)BN_EPS));
        s_w   = bn_w[0];
        s_b   = bn_b[0];
    }
    __syncthreads();
    const float mu = s_mu, inv = s_inv, w = s_w, b = s_b;

    double sig = 0.0;
    for (long long i = tid0; i < E; i += nthreads) {
        const float L = logits[i];
        const float z = w * (L - mu) * inv + b;
        logits[i] = z;
        const float sg = 1.0f / (1.0f + expf(-z));
        ew[i] = sg;
        sig += (double)sg;
    }

    __shared__ double sS[256];
    sS[threadIdx.x] = sig;
    __syncthreads();
    for (int ofs = 128; ofs >= 1; ofs >>= 1) {
        if ((int)threadIdx.x < ofs)
            sS[threadIdx.x] += sS[threadIdx.x + ofs];
        __syncthreads();
    }
    if (threadIdx.x == 0)
        atomicAdd(sig_acc, sS[0]);
}

// ---------------------------------------------------------------------------
// K3: ew *= E / sum_sigmoid (in place, vectorized)
// ---------------------------------------------------------------------------
__global__ void norm_kernel(float* __restrict__ ew,
                            const double* __restrict__ sig_acc,
                            long long E)
{
    const long long nthreads = (long long)gridDim.x * blockDim.x;
    const long long tid0 = (long long)blockIdx.x * blockDim.x + threadIdx.x;
    const float scale = (float)((double)E / sig_acc[0]);

    const long long nvec = E / 4;
    for (long long i = tid0; i < nvec; i += nthreads) {
        float4 v = ((float4*)ew)[i];
        v.x *= scale; v.y *= scale; v.z *= scale; v.w *= scale;
        ((float4*)ew)[i] = v;
    }
    for (long long i = nvec * 4 + tid0; i < E; i += nthreads)
        ew[i] *= scale;
}

extern "C" void kernel_launch(void* const* d_in, const int* in_sizes, int n_in,
                              void* d_out, int out_size, void* d_ws, size_t ws_size,
                              hipStream_t stream) {
    const float* src  = (const float*)d_in[0];
    const float* dst  = (const float*)d_in[1];
    const int*   g    = (const int*)d_in[2];
    const float* bn_w = (const float*)d_in[3];
    const float* bn_b = (const float*)d_in[4];

    const long long N = (long long)in_sizes[0] / EMB_D;
    const long long E = (long long)in_sizes[2] / 2;

    float* out        = (float*)d_out;
    float* out_graph  = out;            // [0, 2E)
    float* out_ew     = out + 2 * E;    // [2E, 3E)
    float* out_logits = out + 3 * E;    // [3E, 4E)  (holds L temporarily)

    double* acc = (double*)d_ws;        // acc[0]=sumL acc[1]=sumL2 acc[2]=sumSig
    unsigned char* src8 = (unsigned char*)d_ws + 256;
    unsigned char* dst8 = src8 + (size_t)N * EMB_D;
    const size_t need = 256 + (size_t)N * EMB_D * 2;

    if (ws_size >= need) {
        // fp8 path: prep (convert + graph copy + acc zero) -> gather
        prep_kernel<<<4096, 256, 0, stream>>>(src, dst,
                                              (unsigned int*)src8,
                                              (unsigned int*)dst8,
                                              N * EMB_D, g, out_graph, 2 * E, acc);
        edge_l_fp8_kernel<<<4096, 256, 0, stream>>>(src8, dst8, g, E,
                                                    out_logits, acc);
    } else {
        // fallback: f32 gather path
        hipMemsetAsync(d_ws, 0, 3 * sizeof(double), stream);
        copy_graph_kernel<<<2048, 256, 0, stream>>>(g, out_graph, 2 * E);
        edge_l_kernel<<<4096, 256, 0, stream>>>(src, dst, g, E, out_logits, acc);
    }

    bn_sig_kernel<<<2048, 256, 0, stream>>>(out_logits, out_ew, acc, &acc[2],
                                            bn_w, bn_b, E);
    norm_kernel<<<2048, 256, 0, stream>>>(out_ew, &acc[2], E);
}